// Round 7
// baseline (201.039 us; speedup 1.0000x reference)
//
#include <hip/hip_runtime.h>
#include <hip/hip_bf16.h>

#define BB 4
#define SS 2048
#define DD 1024
#define NH 16
#define NKV 4
#define HD 64
#define MROWS (BB*SS)              // 8192
#define NQKV (NH*HD + 2*NKV*HD)    // 1536
#define KOFF (NH*HD)               // 1024
#define VPAD 76                    // Vs row stride (u16): 152B = 24 mod 128 -> dg-dependent banks

typedef short v8s __attribute__((ext_vector_type(8)));
typedef short v4s __attribute__((ext_vector_type(4)));
typedef float v4f __attribute__((ext_vector_type(4)));
typedef unsigned short u16;
typedef unsigned int u32;

__device__ __forceinline__ float bf2f(u16 u){
  union { float f; u32 i; } x; x.i = ((u32)u) << 16; return x.f;
}
__device__ __forceinline__ u16 f2bf(float f){
  union { __hip_bfloat16 h; u16 u; } x; x.h = __float2bfloat16(f); return x.u;
}
// v_cvt_pk_bf16_f32: D.lo = bf16(lo), D.hi = bf16(hi) (RNE)
__device__ __forceinline__ u32 cvtpk(float lo, float hi){
  u32 r;
  asm("v_cvt_pk_bf16_f32 %0, %1, %2" : "=v"(r) : "v"(lo), "v"(hi));
  return r;
}
__device__ __forceinline__ float fmax3(float a, float b, float c){
  return fmaxf(fmaxf(a, b), c);   // clang fuses to v_max3_f32
}
// async global->LDS, 16B per lane; lds dest is wave-uniform base + lane*16
__device__ __forceinline__ void gl_lds16(const u16* g, u16* l){
  __builtin_amdgcn_global_load_lds(
      (const __attribute__((address_space(1))) u32*)g,
      (__attribute__((address_space(3))) u32*)l, 16, 0, 0);
}

// ---------------- prep kernels ----------------

__global__ void cast_x(const float* __restrict__ in, u16* __restrict__ out, int n4){
  int i = blockIdx.x*256 + threadIdx.x;
  if (i >= n4) return;
  float4 v = reinterpret_cast<const float4*>(in)[i];
  ushort4 o;
  o.x = f2bf(v.x); o.y = f2bf(v.y); o.z = f2bf(v.z); o.w = f2bf(v.w);
  reinterpret_cast<ushort4*>(out)[i] = o;
}

__global__ void build_bqkv(const float* __restrict__ Wq, const float* __restrict__ Wk,
                           const float* __restrict__ Wv, const float* __restrict__ bq,
                           const float* __restrict__ bk, const float* __restrict__ bv,
                           u16* __restrict__ Bt, float* __restrict__ bias){
  int idx = blockIdx.x*256 + threadIdx.x;   // over 1536*1024
  int n = idx >> 10, k = idx & 1023;
  float v;
  if (n < 1024)      v = Wq[k*1024 + n];
  else if (n < 1280) v = Wk[k*256 + (n-1024)];
  else               v = Wv[k*256 + (n-1280)];
  Bt[idx] = f2bf(v);
  if (k == 0) bias[n] = (n < 1024) ? bq[n] : (n < 1280 ? bk[n-1024] : bv[n-1280]);
}

__global__ void build_wo(const float* __restrict__ Wo, u16* __restrict__ Bt){
  int idx = blockIdx.x*256 + threadIdx.x;   // over 1024*1024
  int n = idx >> 10, k = idx & 1023;
  Bt[idx] = f2bf(Wo[k*1024 + n]);
}

// RoPE in place on K heads only (Q is roped in-register inside attn_k).
__global__ void rope_k(u16* __restrict__ QKV, const float* __restrict__ fr){
  int idx = blockIdx.x*256 + threadIdx.x;   // MROWS*4*32
  int d  = idx & 31;
  int hh = (idx >> 5) & 3;
  long row = idx >> 7;
  int col = KOFF + hh*HD + d;
  u16* p = QKV + row*NQKV;
  float x1 = bf2f(p[col]);
  float x2 = bf2f(p[col+32]);
  float f = fr[row*32 + d];
  float sn, cs; __sincosf(f, &sn, &cs);
  p[col]    = f2bf(x1*cs - x2*sn);
  p[col+32] = f2bf(x2*cs + x1*sn);
}

// ---------------- GEMM (m97 structure): C = A @ Bt^T (+bias) ----------------

template<bool BIAS, typename OT>
__global__ __launch_bounds__(256) void gemm_bt(
    const u16* __restrict__ A, const u16* __restrict__ Bt,
    const float* __restrict__ bias, OT* __restrict__ C,
    int K, int ldc)
{
  __shared__ u16 As[128*32];
  __shared__ u16 Bs[128*32];
  const int tid = threadIdx.x;
  const int wid = tid >> 6, lane = tid & 63;
  const int g = lane >> 4, c = lane & 15;
  const long brow = (long)blockIdx.y * 128;
  const long bcol = (long)blockIdx.x * 128;
  const int wr = (wid >> 1) * 64, wc = (wid & 1) * 64;
  const int srow = tid >> 2;
  const int scol = (tid & 3) * 8;
  const u16* ga = &A [(brow + srow)*K + scol];
  const u16* gb = &Bt[(bcol + srow)*K + scol];
  u16* la = &As[(wid*64)*8];       // HW adds lane*16B
  u16* lb = &Bs[(wid*64)*8];
  v4f acc[4][4] = {};
  for (int kt = 0; kt < K; kt += 32) {
    __syncthreads();
    gl_lds16(ga + kt,          la);
    gl_lds16(ga + 64*K + kt,   la + 256*8);
    gl_lds16(gb + kt,          lb);
    gl_lds16(gb + 64*K + kt,   lb + 256*8);
    __syncthreads();
    v8s af[4], bf[4];
    #pragma unroll
    for (int m=0;m<4;m++) af[m] = *reinterpret_cast<const v8s*>(&As[(wr + m*16 + c)*32 + g*8]);
    #pragma unroll
    for (int n=0;n<4;n++) bf[n] = *reinterpret_cast<const v8s*>(&Bs[(wc + n*16 + c)*32 + g*8]);
    __builtin_amdgcn_s_setprio(1);
    #pragma unroll
    for (int m=0;m<4;m++)
      #pragma unroll
      for (int n=0;n<4;n++)
        acc[m][n] = __builtin_amdgcn_mfma_f32_16x16x32_bf16(af[m], bf[n], acc[m][n], 0,0,0);
    __builtin_amdgcn_s_setprio(0);
  }
  #pragma unroll
  for (int m=0;m<4;m++)
    #pragma unroll
    for (int n=0;n<4;n++) {
      int col = (int)bcol + wc + n*16 + c;
      float badd = BIAS ? bias[col] : 0.0f;
      #pragma unroll
      for (int r2=0;r2<4;r2++){
        long row = brow + wr + m*16 + g*4 + r2;
        float v = acc[m][n][r2] + badd;
        if constexpr (sizeof(OT)==2) C[row*ldc + col] = (OT)f2bf(v);
        else                         C[row*ldc + col] = (OT)v;
      }
    }
}

// ---------------- flash attention ----------------
// grid = B*NH*(S/128); 256 thr = 4 waves, each wave: 32 q-rows; 64-key tiles.
// Swapped QK^T (acc pre-init to -m folds the max subtraction); zero-shuffle PV
// via V slot permutation; l summed by MFMA ones-fragment; double-buffered LDS
// (1 barrier/tile); Q roped in-register (scale*log2e folded); defer-max THR=8.

__global__ __launch_bounds__(256) void attn_k(const u16* __restrict__ QKV,
                                              const float* __restrict__ fr,
                                              u16* __restrict__ Out){
  __shared__ u16 Ks[2][64][72];     // K natural (key, d)
  __shared__ u16 Vs[2][64][VPAD];   // V transposed (d, slot) + XOR-8 bank swizzle
  const int tid = threadIdx.x;
  const int wid = tid >> 6, lane = tid & 63;
  const int g = lane >> 4, c = lane & 15;
  const int qt = blockIdx.x & 15;          // 16 q-tiles of 128 rows
  const int bh = blockIdx.x >> 4;
  const int b = bh >> 4, h = bh & 15;
  const int kvh = h >> 2;
  const u16* Qb = QKV + (long)b*SS*NQKV + h*HD;
  const u16* Kb = QKV + (long)b*SS*NQKV + KOFF + kvh*HD;
  const u16* Vb = Kb + NKV*HD;

  // ---- Q load + in-register RoPE (pairs (d, d+32) live in ks=0/ks=1 frags) ----
  const float SCL = 0.125f * 1.44269504088896f;
  v8s qf[2][2];
  #pragma unroll
  for (int qn=0;qn<2;qn++){
    int lrow = qt*128 + wid*32 + qn*16 + c;
    v8s q0 = *reinterpret_cast<const v8s*>(&Qb[(long)lrow*NQKV + g*8]);
    v8s q1 = *reinterpret_cast<const v8s*>(&Qb[(long)lrow*NQKV + 32 + g*8]);
    const float* frp = fr + ((long)b*SS + lrow)*32 + g*8;
    float4 f0 = *reinterpret_cast<const float4*>(frp);
    float4 f1 = *reinterpret_cast<const float4*>(frp + 4);
    float fa[8] = {f0.x,f0.y,f0.z,f0.w,f1.x,f1.y,f1.z,f1.w};
    float r0[8], r1[8];
    #pragma unroll
    for (int j=0;j<8;j++){
      float x1 = bf2f((u16)q0[j]), x2 = bf2f((u16)q1[j]);
      float sn, cs; __sincosf(fa[j], &sn, &cs);
      r0[j] = (x1*cs - x2*sn) * SCL;
      r1[j] = (x2*cs + x1*sn) * SCL;
    }
    union { v8s v; u32 w[4]; } a0, a1;
    #pragma unroll
    for (int wi=0;wi<4;wi++){
      a0.w[wi] = cvtpk(r0[2*wi], r0[2*wi+1]);
      a1.w[wi] = cvtpk(r1[2*wi], r1[2*wi+1]);
    }
    qf[qn][0] = a0.v; qf[qn][1] = a1.v;
  }

  // constant ones B-fragment: B[k][col=c] = (c==0) -> l accumulates in col 0
  v8s onesf;
  {
    short ov = (c==0) ? (short)0x3F80 : (short)0;
    #pragma unroll
    for (int j=0;j<8;j++) onesf[j] = ov;
  }

  v4f o[2][5] = {};                 // [qm][dn], dn=4 is the l column
  float mr[2] = {0.f, 0.f};         // running max (log2 domain); 0-init is safe (defer-max)

  // staging indices (256 threads): K 2 v8s each; V 2 keys x 8 d each
  const int ksrow = tid >> 3;          // 0..31
  const int kscol = (tid & 7) * 8;
  const int key0  = 2*(tid >> 3);      // 0..62 (even)
  const int dg    = tid & 7;
  const int slot0 = 32*(key0>>5) + 8*((key0>>2)&3) + 4*((key0>>4)&1) + (key0&3);
  // scatter: d = dg*8 + j -> d>>3 == dg for all j, so idx is j-invariant
  const int idx0  = (((slot0>>3) ^ dg) << 3) | (slot0 & 7);
  const int vbase = (dg*8)*VPAD + idx0;       // element offset; +j*VPAD per row
  u16* VsF = &Vs[0][0][0];                    // flattened; buffer p at p*64*VPAD

  const u16* kp0 = Kb + (long)ksrow*NQKV + kscol;
  const u16* kp1 = kp0 + 32*NQKV;
  const u16* vp0 = Vb + (long)key0*NQKV + dg*8;
  const u16* vp1 = vp0 + NQKV;

  v8s kreg0, kreg1;
  union { v8s v; u32 w[4]; } vr0, vr1;

  // prologue: stage tile 0 into buffer 0
  {
    kreg0 = *reinterpret_cast<const v8s*>(kp0);
    kreg1 = *reinterpret_cast<const v8s*>(kp1);
    vr0.v = *reinterpret_cast<const v8s*>(vp0);
    vr1.v = *reinterpret_cast<const v8s*>(vp1);
    *reinterpret_cast<v8s*>(&Ks[0][ksrow][kscol])    = kreg0;
    *reinterpret_cast<v8s*>(&Ks[0][32+ksrow][kscol]) = kreg1;
    #pragma unroll
    for (int j=0;j<8;j++){
      u32 pkd = __builtin_amdgcn_perm(vr1.w[j>>1], vr0.w[j>>1],
                                      (j&1) ? 0x07060302u : 0x05040100u);
      *reinterpret_cast<u32*>(&VsF[vbase + j*VPAD]) = pkd;
    }
  }
  __syncthreads();

  int p = 0;
  for (int t = 0; t < SS/64; ++t){
    // issue next tile's global loads before compute (T14)
    if (t+1 < SS/64) {
      long off = (long)(t+1)*64*NQKV;
      kreg0 = *reinterpret_cast<const v8s*>(kp0 + off);
      kreg1 = *reinterpret_cast<const v8s*>(kp1 + off);
      vr0.v = *reinterpret_cast<const v8s*>(vp0 + off);
      vr1.v = *reinterpret_cast<const v8s*>(vp1 + off);
    }

    // S^T = K @ Q^T, accumulator pre-initialized to -m (folds the subtraction)
    v4f st[4][2];
    #pragma unroll
    for (int qn=0;qn<2;qn++){
      v4f mi = {-mr[qn], -mr[qn], -mr[qn], -mr[qn]};
      #pragma unroll
      for (int km=0;km<4;km++) st[km][qn] = mi;
    }
    #pragma unroll
    for (int ks=0;ks<2;ks++){
      v8s kf[4];
      #pragma unroll
      for (int km=0;km<4;km++)
        kf[km] = *reinterpret_cast<const v8s*>(&Ks[p][km*16 + c][ks*32 + g*8]);
      __builtin_amdgcn_s_setprio(1);
      #pragma unroll
      for (int km=0;km<4;km++)
        #pragma unroll
        for (int qn=0;qn<2;qn++)
          st[km][qn] = __builtin_amdgcn_mfma_f32_16x16x32_bf16(kf[km], qf[qn][ks], st[km][qn], 0,0,0);
      __builtin_amdgcn_s_setprio(0);
    }

    // online softmax with defer-max (T13); st already holds score - m_old
    float al[2];
    bool upd[2];
    #pragma unroll
    for (int qn=0;qn<2;qn++){
      float t0 = fmax3(st[0][qn][0], st[0][qn][1], st[0][qn][2]);
      float t1 = fmax3(st[0][qn][3], st[1][qn][0], st[1][qn][1]);
      float t2 = fmax3(st[1][qn][2], st[1][qn][3], st[2][qn][0]);
      float t3 = fmax3(st[2][qn][1], st[2][qn][2], st[2][qn][3]);
      float t4 = fmax3(st[3][qn][0], st[3][qn][1], st[3][qn][2]);
      float mx = fmaxf(fmax3(t0, t1, t2), fmax3(t3, t4, st[3][qn][3]));
      upd[qn] = !__all(mx <= 8.0f);
      al[qn] = 1.0f;
      if (upd[qn]) {
        mx = fmaxf(mx, __shfl_xor(mx, 16));
        mx = fmaxf(mx, __shfl_xor(mx, 32));
        float d = fmaxf(mx, 0.0f);
        al[qn] = __builtin_amdgcn_exp2f(-d);
        mr[qn] += d;
        #pragma unroll
        for (int km=0;km<4;km++)
          #pragma unroll
          for (int r2=0;r2<4;r2++)
            st[km][qn][r2] -= d;
      }
      #pragma unroll
      for (int km=0;km<4;km++)
        #pragma unroll
        for (int r2=0;r2<4;r2++)
          st[km][qn][r2] = __builtin_amdgcn_exp2f(st[km][qn][r2]);
    }

    // pack P into PV A-frags entirely in-lane
    v8s pa[2][2];
    #pragma unroll
    for (int qm=0;qm<2;qm++)
      #pragma unroll
      for (int ks=0;ks<2;ks++){
        union { v8s v; u32 w[4]; } u;
        u.w[0] = cvtpk(st[2*ks  ][qm][0], st[2*ks  ][qm][1]);
        u.w[1] = cvtpk(st[2*ks  ][qm][2], st[2*ks  ][qm][3]);
        u.w[2] = cvtpk(st[2*ks+1][qm][0], st[2*ks+1][qm][1]);
        u.w[3] = cvtpk(st[2*ks+1][qm][2], st[2*ks+1][qm][3]);
        pa[qm][ks] = u.v;
      }

    // O (incl. l column) rescale only when max moved (wave-uniform branch)
    if (upd[0] | upd[1]) {
      #pragma unroll
      for (int qm=0;qm<2;qm++)
        #pragma unroll
        for (int r2=0;r2<4;r2++){
          float a = __shfl(al[qm], g*4 + r2);
          #pragma unroll
          for (int dn=0;dn<5;dn++) o[qm][dn][r2] *= a;
        }
    }

    // O += P @ V ; l += P @ ones
    #pragma unroll
    for (int ks=0;ks<2;ks++){
      __builtin_amdgcn_s_setprio(1);
      #pragma unroll
      for (int dn=0;dn<4;dn++){
        int d0 = dn*16 + c;
        v8s vf = *reinterpret_cast<const v8s*>(&Vs[p][d0][(((ks*4+g) ^ (d0>>3)) << 3)]);
        #pragma unroll
        for (int qm=0;qm<2;qm++)
          o[qm][dn] = __builtin_amdgcn_mfma_f32_16x16x32_bf16(pa[qm][ks], vf, o[qm][dn], 0,0,0);
      }
      #pragma unroll
      for (int qm=0;qm<2;qm++)
        o[qm][4] = __builtin_amdgcn_mfma_f32_16x16x32_bf16(pa[qm][ks], onesf, o[qm][4], 0,0,0);
      __builtin_amdgcn_s_setprio(0);
    }

    // stage next tile into the other buffer (overlaps other waves' compute)
    if (t+1 < SS/64) {
      *reinterpret_cast<v8s*>(&Ks[p^1][ksrow][kscol])    = kreg0;
      *reinterpret_cast<v8s*>(&Ks[p^1][32+ksrow][kscol]) = kreg1;
      const int bofs = (p^1) * (64*VPAD);
      #pragma unroll
      for (int j=0;j<8;j++){
        u32 pkd = __builtin_amdgcn_perm(vr1.w[j>>1], vr0.w[j>>1],
                                        (j&1) ? 0x07060302u : 0x05040100u);
        *reinterpret_cast<u32*>(&VsF[bofs + vbase + j*VPAD]) = pkd;
      }
    }
    __syncthreads();
    p ^= 1;
  }

  // epilogue: l lives in o[qm][4][r2] at lanes c==0 (lane = g*16); broadcast + store
  #pragma unroll
  for (int qm=0;qm<2;qm++)
    #pragma unroll
    for (int r2=0;r2<4;r2++){
      float l = __shfl(o[qm][4][r2], lane & 48);
      float inv = 1.0f / l;
      long row = (long)b*SS + qt*128 + wid*32 + qm*16 + g*4 + r2;
      #pragma unroll
      for (int dn=0;dn<4;dn++)
        Out[row*DD + h*HD + dn*16 + c] = f2bf(o[qm][dn][r2] * inv);
    }
}

// ---------------- launch ----------------

extern "C" void kernel_launch(void* const* d_in, const int* in_sizes, int n_in,
                              void* d_out, int out_size, void* d_ws, size_t ws_size,
                              hipStream_t stream)
{
  const float* hs = (const float*)d_in[0];
  const float* fr = (const float*)d_in[1];
  const float* Wq = (const float*)d_in[2];
  const float* bq = (const float*)d_in[3];
  const float* Wk = (const float*)d_in[4];
  const float* bk = (const float*)d_in[5];
  const float* Wv = (const float*)d_in[6];
  const float* bv = (const float*)d_in[7];
  const float* Wo = (const float*)d_in[8];
  float* out = (float*)d_out;
  char* ws = (char*)d_ws;

  u16*   Xb   = (u16*)(ws);                                   // 16 MiB
  u16*   Bqkv = (u16*)(ws + 16777216);                        // 3 MiB
  u16*   WoT  = (u16*)(ws + 16777216 + 3145728);              // 2 MiB
  float* bias = (float*)(ws + 16777216 + 3145728 + 2097152);  // 8 KiB
  u16*   QKV  = (u16*)(ws + 22028288);                        // 24 MiB
  u16*   AO   = (u16*)(ws + 22028288 + 25165824);             // 16 MiB

  cast_x   <<<8192, 256, 0, stream>>>(hs, Xb, MROWS*DD/4);
  build_bqkv<<<6144, 256, 0, stream>>>(Wq, Wk, Wv, bq, bk, bv, Bqkv, bias);
  build_wo <<<4096, 256, 0, stream>>>(Wo, WoT);
  gemm_bt<true,  u16>  <<<dim3(NQKV/128, MROWS/128), 256, 0, stream>>>(Xb, Bqkv, bias, QKV, DD, NQKV);
  rope_k   <<<MROWS*NKV*32/256, 256, 0, stream>>>(QKV, fr);
  attn_k   <<<BB*NH*(SS/128), 256, 0, stream>>>(QKV, fr, AO);
  gemm_bt<false, float><<<dim3(DD/128, MROWS/128), 256, 0, stream>>>(AO, WoT, nullptr, out, DD, DD);
}

// Round 8
// 177.413 us; speedup vs baseline: 1.1332x; 1.1332x over previous
//
#include <hip/hip_runtime.h>
#include <hip/hip_bf16.h>

#define BB 4
#define SS 2048
#define DD 1024
#define NH 16
#define NKV 4
#define HD 64
#define MROWS (BB*SS)              // 8192
#define NQKV (NH*HD + 2*NKV*HD)    // 1536
#define KOFF (NH*HD)               // 1024

typedef short v8s __attribute__((ext_vector_type(8)));
typedef short v4s __attribute__((ext_vector_type(4)));
typedef float v4f __attribute__((ext_vector_type(4)));
typedef unsigned short u16;
typedef unsigned int u32;

__device__ __forceinline__ float bf2f(u16 u){
  union { float f; u32 i; } x; x.i = ((u32)u) << 16; return x.f;
}
__device__ __forceinline__ u16 f2bf(float f){
  union { __hip_bfloat16 h; u16 u; } x; x.h = __float2bfloat16(f); return x.u;
}
// v_cvt_pk_bf16_f32: D.lo = bf16(lo), D.hi = bf16(hi) (RNE)
__device__ __forceinline__ u32 cvtpk(float lo, float hi){
  u32 r;
  asm("v_cvt_pk_bf16_f32 %0, %1, %2" : "=v"(r) : "v"(lo), "v"(hi));
  return r;
}
__device__ __forceinline__ float fmax3(float a, float b, float c){
  return fmaxf(fmaxf(a, b), c);   // clang fuses to v_max3_f32
}
// async global->LDS, 16B per lane; lds dest is wave-uniform base + lane*16
__device__ __forceinline__ void gl_lds16(const u16* g, u16* l){
  __builtin_amdgcn_global_load_lds(
      (const __attribute__((address_space(1))) u32*)g,
      (__attribute__((address_space(3))) u32*)l, 16, 0, 0);
}

// ---------------- prep kernels ----------------

__global__ void cast_x(const float* __restrict__ in, u16* __restrict__ out, int n4){
  int i = blockIdx.x*256 + threadIdx.x;
  if (i >= n4) return;
  float4 v = reinterpret_cast<const float4*>(in)[i];
  ushort4 o;
  o.x = f2bf(v.x); o.y = f2bf(v.y); o.z = f2bf(v.z); o.w = f2bf(v.w);
  reinterpret_cast<ushort4*>(out)[i] = o;
}

__global__ void build_bqkv(const float* __restrict__ Wq, const float* __restrict__ Wk,
                           const float* __restrict__ Wv, const float* __restrict__ bq,
                           const float* __restrict__ bk, const float* __restrict__ bv,
                           u16* __restrict__ Bt, float* __restrict__ bias){
  int idx = blockIdx.x*256 + threadIdx.x;   // over 1536*1024
  int n = idx >> 10, k = idx & 1023;
  float v;
  if (n < 1024)      v = Wq[k*1024 + n];
  else if (n < 1280) v = Wk[k*256 + (n-1024)];
  else               v = Wv[k*256 + (n-1280)];
  Bt[idx] = f2bf(v);
  if (k == 0) bias[n] = (n < 1024) ? bq[n] : (n < 1280 ? bk[n-1024] : bv[n-1280]);
}

__global__ void build_wo(const float* __restrict__ Wo, u16* __restrict__ Bt){
  int idx = blockIdx.x*256 + threadIdx.x;   // over 1024*1024
  int n = idx >> 10, k = idx & 1023;
  Bt[idx] = f2bf(Wo[k*1024 + n]);
}

// RoPE in place on K heads only (Q is roped in-register inside attn_k).
__global__ void rope_k(u16* __restrict__ QKV, const float* __restrict__ fr){
  int idx = blockIdx.x*256 + threadIdx.x;   // MROWS*4*32
  int d  = idx & 31;
  int hh = (idx >> 5) & 3;
  long row = idx >> 7;
  int col = KOFF + hh*HD + d;
  u16* p = QKV + row*NQKV;
  float x1 = bf2f(p[col]);
  float x2 = bf2f(p[col+32]);
  float f = fr[row*32 + d];
  float sn, cs; __sincosf(f, &sn, &cs);
  p[col]    = f2bf(x1*cs - x2*sn);
  p[col+32] = f2bf(x2*cs + x1*sn);
}

// ---------------- GEMM (m97 structure, BK=64): C = A @ Bt^T (+bias) ----------------
// A (M,K) bf16 row-major, Bt (N,K) bf16. 128x128 tile, BK=64, linear LDS,
// global_load_lds width-16 staging; one barrier pair per 64-K step.

template<bool BIAS, typename OT>
__global__ __launch_bounds__(256) void gemm_bt(
    const u16* __restrict__ A, const u16* __restrict__ Bt,
    const float* __restrict__ bias, OT* __restrict__ C,
    int K, int ldc)
{
  __shared__ u16 As[128*64];
  __shared__ u16 Bs[128*64];
  const int tid = threadIdx.x;
  const int wid = tid >> 6, lane = tid & 63;
  const int g = lane >> 4, c = lane & 15;
  const long brow = (long)blockIdx.y * 128;
  const long bcol = (long)blockIdx.x * 128;
  const int wr = (wid >> 1) * 64, wc = (wid & 1) * 64;
  // staging: 4 chunks of 32 rows per operand; row = e*32 + (tid>>3), col = (tid&7)*8
  const int srow = tid >> 3;           // 0..31
  const int scol = (tid & 7) * 8;
  const u16* ga = &A [(brow + srow)*K + scol];
  const u16* gb = &Bt[(bcol + srow)*K + scol];
  u16* la = &As[(wid*8)*64];           // HW adds lane*16B; chunk e adds 32 rows
  u16* lb = &Bs[(wid*8)*64];
  v4f acc[4][4] = {};
  for (int kt = 0; kt < K; kt += 64) {
    __syncthreads();
    #pragma unroll
    for (int e = 0; e < 4; ++e) {
      gl_lds16(ga + (long)e*32*K + kt, la + e*32*64);
      gl_lds16(gb + (long)e*32*K + kt, lb + e*32*64);
    }
    __syncthreads();
    #pragma unroll
    for (int ks = 0; ks < 2; ++ks) {
      v8s af[4], bf[4];
      #pragma unroll
      for (int m=0;m<4;m++) af[m] = *reinterpret_cast<const v8s*>(&As[(wr + m*16 + c)*64 + ks*32 + g*8]);
      #pragma unroll
      for (int n=0;n<4;n++) bf[n] = *reinterpret_cast<const v8s*>(&Bs[(wc + n*16 + c)*64 + ks*32 + g*8]);
      __builtin_amdgcn_s_setprio(1);
      #pragma unroll
      for (int m=0;m<4;m++)
        #pragma unroll
        for (int n=0;n<4;n++)
          acc[m][n] = __builtin_amdgcn_mfma_f32_16x16x32_bf16(af[m], bf[n], acc[m][n], 0,0,0);
      __builtin_amdgcn_s_setprio(0);
    }
  }
  #pragma unroll
  for (int m=0;m<4;m++)
    #pragma unroll
    for (int n=0;n<4;n++) {
      int col = (int)bcol + wc + n*16 + c;
      float badd = BIAS ? bias[col] : 0.0f;
      #pragma unroll
      for (int r2=0;r2<4;r2++){
        long row = brow + wr + m*16 + g*4 + r2;
        float v = acc[m][n][r2] + badd;
        if constexpr (sizeof(OT)==2) C[row*ldc + col] = (OT)f2bf(v);
        else                         C[row*ldc + col] = (OT)v;
      }
    }
}

// ---------------- flash attention ----------------
// grid = B*NH*(S/256); 512 thr = 8 waves, each wave: 32 q-rows; 64-key tiles.
// Swapped QK^T (acc pre-init to -m folds the max subtraction); zero-shuffle PV
// via V slot permutation; l summed by MFMA ones-fragment; double-buffered LDS
// (1 barrier/tile); Q roped in-register (scale*log2e folded); defer-max THR=8.

__global__ __launch_bounds__(512) void attn_k(const u16* __restrict__ QKV,
                                              const float* __restrict__ fr,
                                              u16* __restrict__ Out){
  __shared__ u16 Ks[2][64][72];   // K natural (key, d)
  __shared__ u16 Vs[2][64][72];   // V transposed (d, slot) + XOR-8 bank swizzle
  const int tid = threadIdx.x;
  const int wid = tid >> 6, lane = tid & 63;
  const int g = lane >> 4, c = lane & 15;
  const int qt = blockIdx.x & 7;           // 8 q-tiles of 256 rows
  const int bh = blockIdx.x >> 3;
  const int b = bh >> 4, h = bh & 15;
  const int kvh = h >> 2;
  const u16* Qb = QKV + (long)b*SS*NQKV + h*HD;
  const u16* Kb = QKV + (long)b*SS*NQKV + KOFF + kvh*HD;
  const u16* Vb = Kb + NKV*HD;

  // ---- Q load + in-register RoPE (pairs (d, d+32) live in ks=0/ks=1 frags) ----
  const float SCL = 0.125f * 1.44269504088896f;
  v8s qf[2][2];
  #pragma unroll
  for (int qn=0;qn<2;qn++){
    int lrow = qt*256 + wid*32 + qn*16 + c;
    v8s q0 = *reinterpret_cast<const v8s*>(&Qb[(long)lrow*NQKV + g*8]);
    v8s q1 = *reinterpret_cast<const v8s*>(&Qb[(long)lrow*NQKV + 32 + g*8]);
    const float* frp = fr + ((long)b*SS + lrow)*32 + g*8;
    float4 f0 = *reinterpret_cast<const float4*>(frp);
    float4 f1 = *reinterpret_cast<const float4*>(frp + 4);
    float fa[8] = {f0.x,f0.y,f0.z,f0.w,f1.x,f1.y,f1.z,f1.w};
    float r0[8], r1[8];
    #pragma unroll
    for (int j=0;j<8;j++){
      float x1 = bf2f((u16)q0[j]), x2 = bf2f((u16)q1[j]);
      float sn, cs; __sincosf(fa[j], &sn, &cs);
      r0[j] = (x1*cs - x2*sn) * SCL;
      r1[j] = (x2*cs + x1*sn) * SCL;
    }
    union { v8s v; u32 w[4]; } a0, a1;
    #pragma unroll
    for (int wi=0;wi<4;wi++){
      a0.w[wi] = cvtpk(r0[2*wi], r0[2*wi+1]);
      a1.w[wi] = cvtpk(r1[2*wi], r1[2*wi+1]);
    }
    qf[qn][0] = a0.v; qf[qn][1] = a1.v;
  }

  // constant ones B-fragment: B[k][col=c] = (c==0) -> l accumulates in col 0
  v8s onesf;
  {
    short ov = (c==0) ? (short)0x3F80 : (short)0;
    #pragma unroll
    for (int j=0;j<8;j++) onesf[j] = ov;
  }

  v4f o[2][5] = {};                 // [qm][dn], dn=4 is the l column
  float mr[2] = {0.f, 0.f};         // running max (log2 domain); 0-init safe (defer-max)

  // staging indices (512 threads): K one v8s each; V 2 keys x 4 d each
  const int krow = tid >> 3;           // 0..63
  const int kcol = (tid & 7) * 8;
  const int key0 = 2*(tid >> 4);       // 0..62 (even)
  const int dg4  = (tid & 15) * 4;     // 0..60
  const int slot0 = 32*(key0>>5) + 8*((key0>>2)&3) + 4*((key0>>4)&1) + (key0&3);
  int vofs[4];
  #pragma unroll
  for (int j=0;j<4;j++){
    int d = dg4 + j;
    int idx = (((slot0>>3) ^ (d>>3)) << 3) | (slot0 & 7);
    vofs[j] = d*72 + idx;
  }
  u16* VsF = &Vs[0][0][0];           // flattened; buffer p at offset p*64*72

  const u16* kp  = Kb + (long)krow*NQKV + kcol;
  const u16* vp0 = Vb + (long)key0*NQKV + dg4;
  const u16* vp1 = vp0 + NQKV;

  v8s kreg;
  union { v4s v; u32 w[2]; } vr0, vr1;

  // prologue: stage tile 0 into buffer 0
  {
    kreg  = *reinterpret_cast<const v8s*>(kp);
    vr0.v = *reinterpret_cast<const v4s*>(vp0);
    vr1.v = *reinterpret_cast<const v4s*>(vp1);
    *reinterpret_cast<v8s*>(&Ks[0][krow][kcol]) = kreg;
    #pragma unroll
    for (int j=0;j<4;j++){
      u32 pkd = __builtin_amdgcn_perm(vr1.w[j>>1], vr0.w[j>>1],
                                      (j&1) ? 0x07060302u : 0x05040100u);
      *reinterpret_cast<u32*>(&VsF[vofs[j]]) = pkd;
    }
  }
  __syncthreads();

  int p = 0;
  for (int t = 0; t < SS/64; ++t){
    // issue next tile's global loads before compute (T14)
    if (t+1 < SS/64) {
      long off = (long)(t+1)*64*NQKV;
      kreg  = *reinterpret_cast<const v8s*>(kp  + off);
      vr0.v = *reinterpret_cast<const v4s*>(vp0 + off);
      vr1.v = *reinterpret_cast<const v4s*>(vp1 + off);
    }

    // S^T = K @ Q^T, accumulator pre-initialized to -m (folds the subtraction)
    v4f st[4][2];
    #pragma unroll
    for (int qn=0;qn<2;qn++){
      v4f mi = {-mr[qn], -mr[qn], -mr[qn], -mr[qn]};
      #pragma unroll
      for (int km=0;km<4;km++) st[km][qn] = mi;
    }
    #pragma unroll
    for (int ks=0;ks<2;ks++){
      v8s kf[4];
      #pragma unroll
      for (int km=0;km<4;km++)
        kf[km] = *reinterpret_cast<const v8s*>(&Ks[p][km*16 + c][ks*32 + g*8]);
      __builtin_amdgcn_s_setprio(1);
      #pragma unroll
      for (int km=0;km<4;km++)
        #pragma unroll
        for (int qn=0;qn<2;qn++)
          st[km][qn] = __builtin_amdgcn_mfma_f32_16x16x32_bf16(kf[km], qf[qn][ks], st[km][qn], 0,0,0);
      __builtin_amdgcn_s_setprio(0);
    }

    // online softmax with defer-max (T13); st already holds score - m_old
    float al[2];
    bool upd[2];
    #pragma unroll
    for (int qn=0;qn<2;qn++){
      float t0 = fmax3(st[0][qn][0], st[0][qn][1], st[0][qn][2]);
      float t1 = fmax3(st[0][qn][3], st[1][qn][0], st[1][qn][1]);
      float t2 = fmax3(st[1][qn][2], st[1][qn][3], st[2][qn][0]);
      float t3 = fmax3(st[2][qn][1], st[2][qn][2], st[2][qn][3]);
      float t4 = fmax3(st[3][qn][0], st[3][qn][1], st[3][qn][2]);
      float mx = fmaxf(fmax3(t0, t1, t2), fmax3(t3, t4, st[3][qn][3]));
      upd[qn] = !__all(mx <= 8.0f);
      al[qn] = 1.0f;
      if (upd[qn]) {
        mx = fmaxf(mx, __shfl_xor(mx, 16));
        mx = fmaxf(mx, __shfl_xor(mx, 32));
        float d = fmaxf(mx, 0.0f);
        al[qn] = __builtin_amdgcn_exp2f(-d);
        mr[qn] += d;
        #pragma unroll
        for (int km=0;km<4;km++)
          #pragma unroll
          for (int r2=0;r2<4;r2++)
            st[km][qn][r2] -= d;
      }
      #pragma unroll
      for (int km=0;km<4;km++)
        #pragma unroll
        for (int r2=0;r2<4;r2++)
          st[km][qn][r2] = __builtin_amdgcn_exp2f(st[km][qn][r2]);
    }

    // pack P into PV A-frags entirely in-lane
    v8s pa[2][2];
    #pragma unroll
    for (int qm=0;qm<2;qm++)
      #pragma unroll
      for (int ks=0;ks<2;ks++){
        union { v8s v; u32 w[4]; } u;
        u.w[0] = cvtpk(st[2*ks  ][qm][0], st[2*ks  ][qm][1]);
        u.w[1] = cvtpk(st[2*ks  ][qm][2], st[2*ks  ][qm][3]);
        u.w[2] = cvtpk(st[2*ks+1][qm][0], st[2*ks+1][qm][1]);
        u.w[3] = cvtpk(st[2*ks+1][qm][2], st[2*ks+1][qm][3]);
        pa[qm][ks] = u.v;
      }

    // O (incl. l column) rescale only when max moved (wave-uniform branch)
    if (upd[0] | upd[1]) {
      #pragma unroll
      for (int qm=0;qm<2;qm++)
        #pragma unroll
        for (int r2=0;r2<4;r2++){
          float a = __shfl(al[qm], g*4 + r2);
          #pragma unroll
          for (int dn=0;dn<5;dn++) o[qm][dn][r2] *= a;
        }
    }

    // O += P @ V ; l += P @ ones
    #pragma unroll
    for (int ks=0;ks<2;ks++){
      __builtin_amdgcn_s_setprio(1);
      #pragma unroll
      for (int dn=0;dn<4;dn++){
        int d0 = dn*16 + c;
        v8s vf = *reinterpret_cast<const v8s*>(&Vs[p][d0][(((ks*4+g) ^ (d0>>3)) << 3)]);
        #pragma unroll
        for (int qm=0;qm<2;qm++)
          o[qm][dn] = __builtin_amdgcn_mfma_f32_16x16x32_bf16(pa[qm][ks], vf, o[qm][dn], 0,0,0);
      }
      #pragma unroll
      for (int qm=0;qm<2;qm++)
        o[qm][4] = __builtin_amdgcn_mfma_f32_16x16x32_bf16(pa[qm][ks], onesf, o[qm][4], 0,0,0);
      __builtin_amdgcn_s_setprio(0);
    }

    // stage next tile into the other buffer (overlaps other waves' compute)
    if (t+1 < SS/64) {
      *reinterpret_cast<v8s*>(&Ks[p^1][krow][kcol]) = kreg;
      const int bofs = (p^1) * (64*72);
      #pragma unroll
      for (int j=0;j<4;j++){
        u32 pkd = __builtin_amdgcn_perm(vr1.w[j>>1], vr0.w[j>>1],
                                        (j&1) ? 0x07060302u : 0x05040100u);
        *reinterpret_cast<u32*>(&VsF[bofs + vofs[j]]) = pkd;
      }
    }
    __syncthreads();
    p ^= 1;
  }

  // epilogue: l lives in o[qm][4][r2] at lanes c==0 (lane = g*16); broadcast + store
  #pragma unroll
  for (int qm=0;qm<2;qm++)
    #pragma unroll
    for (int r2=0;r2<4;r2++){
      float l = __shfl(o[qm][4][r2], lane & 48);
      float inv = 1.0f / l;
      long row = (long)b*SS + qt*256 + wid*32 + qm*16 + g*4 + r2;
      #pragma unroll
      for (int dn=0;dn<4;dn++)
        Out[row*DD + h*HD + dn*16 + c] = f2bf(o[qm][dn][r2] * inv);
    }
}

// ---------------- launch ----------------

extern "C" void kernel_launch(void* const* d_in, const int* in_sizes, int n_in,
                              void* d_out, int out_size, void* d_ws, size_t ws_size,
                              hipStream_t stream)
{
  const float* hs = (const float*)d_in[0];
  const float* fr = (const float*)d_in[1];
  const float* Wq = (const float*)d_in[2];
  const float* bq = (const float*)d_in[3];
  const float* Wk = (const float*)d_in[4];
  const float* bk = (const float*)d_in[5];
  const float* Wv = (const float*)d_in[6];
  const float* bv = (const float*)d_in[7];
  const float* Wo = (const float*)d_in[8];
  float* out = (float*)d_out;
  char* ws = (char*)d_ws;

  u16*   Xb   = (u16*)(ws);                                   // 16 MiB
  u16*   Bqkv = (u16*)(ws + 16777216);                        // 3 MiB
  u16*   WoT  = (u16*)(ws + 16777216 + 3145728);              // 2 MiB
  float* bias = (float*)(ws + 16777216 + 3145728 + 2097152);  // 8 KiB
  u16*   QKV  = (u16*)(ws + 22028288);                        // 24 MiB
  u16*   AO   = (u16*)(ws + 22028288 + 25165824);             // 16 MiB

  cast_x   <<<8192, 256, 0, stream>>>(hs, Xb, MROWS*DD/4);
  build_bqkv<<<6144, 256, 0, stream>>>(Wq, Wk, Wv, bq, bk, bv, Bqkv, bias);
  build_wo <<<4096, 256, 0, stream>>>(Wo, WoT);
  gemm_bt<true,  u16>  <<<dim3(NQKV/128, MROWS/128), 256, 0, stream>>>(Xb, Bqkv, bias, QKV, DD, NQKV);
  rope_k   <<<MROWS*NKV*32/256, 256, 0, stream>>>(QKV, fr);
  attn_k   <<<BB*NH*(SS/256), 512, 0, stream>>>(QKV, fr, AO);
  gemm_bt<false, float><<<dim3(DD/128, MROWS/128), 256, 0, stream>>>(AO, WoT, nullptr, out, DD, DD);
}